// Round 17
// baseline (170.220 us; speedup 1.0000x reference)
//
#include <hip/hip_runtime.h>
#include <hip/hip_bf16.h>

// ChebConv K=3 GCN — Round 17: register-stash lsort, shfl-scan sort, stage-free props.
// R16 post-mortem: 161.5us, all kernels <44us. Three mechanism shaves:
//  (1) lsort stashes its <=4 int4 (src,dst) pairs in registers during the
//      histogram pass and scatters from them — deletes the 12.8MB re-read.
//  (2) sort replaces 32 __syncthreads of H-S scans with wave __shfl_up scans
//      (register-only) + tiny cross-wave fixup -> 5 barriers.
//  (3) props read es directly (node lists contiguous; 4 lanes/quad load the
//      SAME int4 -> hardware broadcast): deletes staging loop+barrier+18KB
//      LDS; occupancy now VGPR-bound; grid decoupled (1563 x 64 nodes).

#define NN   100000
#define NE   3200000
#define F    16
#define CB   128                  // dst nodes per bucket
#define NBUK 782                  // ceil(NN/CB)
#define ECHK 8192                 // edges per sort chunk
#define NBLK 391                  // ceil(NE/ECHK)
#define LCAP 5632                 // per-bucket es slot (padded mean ~4544, >12 sigma)
#define HXW  1025                 // hxg row width (1024 run starts + total)

__device__ __forceinline__ float bflo(unsigned int u) {
    return __uint_as_float(u << 16);
}
__device__ __forceinline__ float bfhi(unsigned int u) {
    return __uint_as_float(u & 0xffff0000u);
}
__device__ __forceinline__ unsigned int f2bf(float f) {
    __hip_bfloat16 b = __float2bfloat16(f);
    return (unsigned int)*reinterpret_cast<unsigned short*>(&b);
}

// A1: per-chunk LDS counting sort by bucket -> chunk-major csort + run table hxg.
// (src,dst) int4 pairs stashed in registers between histogram and scatter.
__global__ __launch_bounds__(512) void k_lsort(const int* __restrict__ src,
        const int* __restrict__ dst, int* __restrict__ hxg, int* __restrict__ csort) {
    __shared__ __align__(16) int pk[ECHK];   // 32KB
    __shared__ int hx[HXW];
    __shared__ int cur[1024];
    __shared__ int csum[512];
    int t = threadIdx.x, blk = blockIdx.x;
    for (int j = t; j < 1024; j += 512) hx[j] = 0;
    __syncthreads();
    int s0 = blk * ECHK;
    int lim = min(s0 + ECHK, NE);
    int n4 = (lim - s0) >> 2;                // 2048 or 1280 (both /4)
    const int4* dst4 = (const int4*)(dst + s0);
    const int4* src4 = (const int4*)(src + s0);
    int4 dreg[4], sreg[4];
#pragma unroll
    for (int k = 0; k < 4; ++k) {
        int i = t + (k << 9);
        if (i < n4) {
            int4 d = dst4[i];
            int4 s = src4[i];
            dreg[k] = d; sreg[k] = s;
            atomicAdd(&hx[d.x >> 7], 1);
            atomicAdd(&hx[d.y >> 7], 1);
            atomicAdd(&hx[d.z >> 7], 1);
            atomicAdd(&hx[d.w >> 7], 1);
        }
    }
    __syncthreads();
    int b0 = t * 2;
    int c0 = hx[b0], c1 = hx[b0 + 1];
    csum[t] = c0 + c1;
    __syncthreads();
    for (int o = 1; o < 512; o <<= 1) {
        int add = (t >= o) ? csum[t - o] : 0;
        __syncthreads();
        csum[t] += add;
        __syncthreads();
    }
    int ce = csum[t] - (c0 + c1);
    hx[b0] = ce;  hx[b0 + 1] = ce + c0;
    cur[b0] = ce; cur[b0 + 1] = ce + c0;
    if (t == 511) hx[1024] = csum[511];
    __syncthreads();
    for (int j = t; j < HXW; j += 512)
        hxg[blk * HXW + j] = hx[j];
#pragma unroll
    for (int k = 0; k < 4; ++k) {
        int i = t + (k << 9);
        if (i < n4) {
            int4 d = dreg[k];
            int4 s = sreg[k];
            int pos;
            pos = atomicAdd(&cur[d.x >> 7], 1); pk[pos] = (s.x << 7) | (d.x & 127);
            pos = atomicAdd(&cur[d.y >> 7], 1); pk[pos] = (s.y << 7) | (d.y & 127);
            pos = atomicAdd(&cur[d.z >> 7], 1); pk[pos] = (s.z << 7) | (d.z & 127);
            pos = atomicAdd(&cur[d.w >> 7], 1); pk[pos] = (s.w << 7) | (d.w & 127);
        }
    }
    __syncthreads();
    int4* cs4 = (int4*)(csort + s0);
    const int4* pk4 = (const int4*)pk;
    for (int i = t; i < n4; i += 512)
        cs4[i] = pk4[i];
}

// A2: per-bucket exact dst sort. Cooperative 16-lane run gather into LDS,
// counting sort with 8-padded node lists (shfl scans), packed CSR, Y0, int4 es.
__global__ __launch_bounds__(512) void k_sort(const int* __restrict__ csort,
        const int* __restrict__ hxg, const float* __restrict__ X0,
        int* __restrict__ es, unsigned int* __restrict__ P,
        unsigned short* __restrict__ Y0, unsigned short* __restrict__ Y1) {
    __shared__ __align__(16) int pk[LCAP];    // 22KB: bucket-grouped (unsorted)
    __shared__ __align__(16) int pk2[LCAP];   // 22KB: dst-sorted, 8-padded
    __shared__ int dsc[512];        // inclusive scan of run lengths
    __shared__ int hS[NBLK];        // run start within chunk
    __shared__ short rls[NBLK];     // run length
    __shared__ int wsum[8];
    __shared__ int ws2[2];
    __shared__ int cnt[CB], loc[CB], cur[CB];
    __shared__ float nvs[CB];
    int b = blockIdx.x, t = threadIdx.x;
    int ln = t & 63, wv = t >> 6;
    int h0 = 0, rl = 0;
    if (t < NBLK) {
        h0 = hxg[t * HXW + b];      // adjacent pair
        rl = hxg[t * HXW + b + 1] - h0;
        hS[t] = h0;
        rls[t] = (short)(rl > 4096 ? 4096 : rl);
    }
    if (t < CB) cnt[t] = 0;
    if (b == 0 && t < 4) {          // zero sentinel rows
        ((uint2*)Y0)[(size_t)NN * 4 + t] = make_uint2(0u, 0u);
        ((uint2*)Y1)[(size_t)NN * 4 + t] = make_uint2(0u, 0u);
    }
    // wave shfl scan of run lengths (inclusive), cross-wave fixup
    int v = rl;
    for (int o = 1; o < 64; o <<= 1) {
        int up = __shfl_up(v, o, 64);
        if (ln >= o) v += up;
    }
    if (ln == 63) wsum[wv] = v;
    __syncthreads();
    if (t == 0) {
        int acc = 0;
        for (int i = 0; i < 8; ++i) { int x = wsum[i]; wsum[i] = acc; acc += x; }
    }
    __syncthreads();
    v += wsum[wv];
    dsc[t] = v;
    __syncthreads();
    int len = dsc[511];
    if (len > LCAP) len = LCAP;
    // cooperative run gather: 32 groups x 16 lanes, coalesced per run
    int g = t >> 4, lane = t & 15;
    for (int c = g; c < NBLK; c += 32) {
        int rlc = rls[c];
        if (rlc == 0) continue;
        int dpos = dsc[c] - rlc;
        if (dpos >= LCAP) continue;
        if (dpos + rlc > LCAP) rlc = LCAP - dpos;
        int sb = c * ECHK + hS[c];
        for (int l = lane; l < rlc; l += 16)
            pk[dpos + l] = csort[sb + l];
    }
    __syncthreads();
    // count dst occupancy
    for (int i = t; i < len; i += 512)
        atomicAdd(&cnt[pk[i] & 127], 1);
    __syncthreads();
    // shfl scan of 8-padded counts -> exclusive offsets (multiples of 8)
    int pc = 0, vv = 0;
    if (t < CB) { pc = (cnt[t] + 7) & ~7; vv = pc; }
    for (int o = 1; o < 64; o <<= 1) {
        int up = __shfl_up(vv, o, 64);
        if (ln >= o) vv += up;
    }
    if (t < CB && ln == 63) ws2[wv] = vv;
    __syncthreads();
    if (t < CB) {
        if (wv == 1) vv += ws2[0];
        int excl = vv - pc;
        loc[t] = excl;
        cur[t] = excl;
        int n = b * CB + t;
        if (n < NN) {
            unsigned dgc = cnt[t] > 1023 ? 1023u : (unsigned)cnt[t];
            P[n] = ((unsigned)((b * LCAP + excl) >> 3) << 10) | dgc;  // off/8 | deg
            nvs[t] = rsqrtf((float)(cnt[t] < 1 ? 1 : cnt[t]));
        }
    }
    __syncthreads();
    int plen = loc[CB - 1] + ((cnt[CB - 1] + 7) & ~7);
    if (plen > LCAP) plen = LCAP;
    // pad fill (disjoint from scatter region)
    if (t < CB) {
        int e0 = loc[t] + cnt[t];
        int e1 = loc[t] + ((cnt[t] + 7) & ~7);
        for (int i = e0; i < e1 && i < LCAP; ++i) pk2[i] = NN;
    }
    // dst-sort scatter from LDS pk
    for (int i = t; i < len; i += 512) {
        int p = pk[i];
        int pos = atomicAdd(&cur[p & 127], 1);
        if (pos < LCAP) pk2[pos] = p >> 7;
    }
    // Y0 for this bucket's nodes (coalesced)
    for (int j = t; j < CB * 4; j += 512) {
        int dl = j >> 2;
        int n = b * CB + dl;
        if (n < NN) {
            float nv = nvs[dl];
            size_t g4 = (size_t)n * 4 + (j & 3);
            float4 x0 = ((const float4*)X0)[g4];
            uint2 o;
            o.x = f2bf(x0.x * nv) | (f2bf(x0.y * nv) << 16);
            o.y = f2bf(x0.z * nv) | (f2bf(x0.w * nv) << 16);
            ((uint2*)Y0)[g4] = o;
        }
    }
    __syncthreads();
    // int4 es writeout (fixed per-bucket slot; base 16B-aligned, plen % 8 == 0)
    int4* es4 = (int4*)(es + b * LCAP);
    const int4* p24 = (const int4*)pk2;
    int p4 = plen >> 2;
    for (int i = t; i < p4; i += 512)
        es4[i] = p24[i];
}

// A3: prop1. 4 lanes/node; es read DIRECTLY as int4 (same addr in a quad ->
// HW broadcast; node lists contiguous -> wave-coalesced). No LDS.
__global__ __launch_bounds__(256) void k_prop1(const unsigned int* __restrict__ P,
        const int* __restrict__ es, const unsigned short* __restrict__ Y0,
        const float* __restrict__ X0, const float* __restrict__ lm,
        unsigned short* __restrict__ Y1) {
    int t = threadIdx.x;
    int n = blockIdx.x * 64 + (t >> 2), h = t & 3;
    if (n >= NN) return;
    unsigned pkn = P[n];
    int begq = (int)(pkn >> 10) << 1;   // es offset in int4 units
    int dg = (int)(pkn & 1023u);
    int nb = (dg + 7) >> 3;
    const int4* esq = (const int4*)es;
    const uint2* Yv = (const uint2*)Y0;
    float a0 = 0.f, a1 = 0.f, a2 = 0.f, a3 = 0.f;
    for (int bb = 0; bb < nb; ++bb) {
        int4 ia = esq[begq + bb * 2];
        int4 ib = esq[begq + bb * 2 + 1];
#define ACC(S) { uint2 u = Yv[(size_t)(S) * 4 + h]; \
                 a0 += bflo(u.x); a1 += bfhi(u.x); \
                 a2 += bflo(u.y); a3 += bfhi(u.y); }
        ACC(ia.x) ACC(ia.y) ACC(ia.z) ACC(ia.w)
        ACC(ib.x) ACC(ib.y) ACC(ib.z) ACC(ib.w)
    }
    float nv = rsqrtf((float)(dg < 1 ? 1 : dg));
    float r  = 2.0f / lm[0];
    float k1 = -r * nv, k2 = r - 1.0f;
    int tid4 = n * 4 + h;
    float4 x0 = ((const float4*)X0)[tid4];
    float x1a = k1 * a0 + k2 * x0.x;
    float x1b = k1 * a1 + k2 * x0.y;
    float x1c = k1 * a2 + k2 * x0.z;
    float x1d = k1 * a3 + k2 * x0.w;
    uint2 o;
    o.x = f2bf(nv * x1a) | (f2bf(nv * x1b) << 16);
    o.y = f2bf(nv * x1c) | (f2bf(nv * x1d) << 16);
    ((uint2*)Y1)[tid4] = o;
}

// A4: prop2 + epilogue: x2 + [x0|x1|x2]@W^T + relu. Direct es reads.
__global__ __launch_bounds__(256) void k_prop2(const unsigned int* __restrict__ P,
        const int* __restrict__ es, const unsigned short* __restrict__ Y1,
        const float* __restrict__ X0, const float* __restrict__ lm,
        const float* __restrict__ W, float* __restrict__ out) {
    __shared__ float Ws[96];
    int t = threadIdx.x;
    if (t < 96) Ws[t] = W[t];
    __syncthreads();
    int n = blockIdx.x * 64 + (t >> 2), h = t & 3;
    if (n >= NN) return;
    unsigned pkn = P[n];
    int begq = (int)(pkn >> 10) << 1;
    int dg = (int)(pkn & 1023u);
    int nb = (dg + 7) >> 3;
    const int4* esq = (const int4*)es;
    const uint2* Yv = (const uint2*)Y1;
    float a0 = 0.f, a1 = 0.f, a2 = 0.f, a3 = 0.f;
    for (int bb = 0; bb < nb; ++bb) {
        int4 ia = esq[begq + bb * 2];
        int4 ib = esq[begq + bb * 2 + 1];
        ACC(ia.x) ACC(ia.y) ACC(ia.z) ACC(ia.w)
        ACC(ib.x) ACC(ib.y) ACC(ib.z) ACC(ib.w)
    }
    int dc = dg < 1 ? 1 : dg;
    float nv = rsqrtf((float)dc);
    float rn = sqrtf((float)dc);    // 1/nv without rcp
    float r  = 2.0f / lm[0];
    int tid4 = n * 4 + h;
    float4 x0 = ((const float4*)X0)[tid4];
    uint2 uy = ((const uint2*)Y1)[tid4];
    float x1a = bflo(uy.x) * rn, x1b = bfhi(uy.x) * rn;
    float x1c = bflo(uy.y) * rn, x1d = bfhi(uy.y) * rn;
    float c1 = -2.0f * r * nv, c2 = 2.0f * (r - 1.0f);
    float x2a = c1 * a0 + c2 * x1a - x0.x;
    float x2b = c1 * a1 + c2 * x1b - x0.y;
    float x2c = c1 * a2 + c2 * x1c - x0.z;
    float x2d = c1 * a3 + c2 * x1d - x0.w;
    int f0 = 4 * h;
    float t0 = Ws[f0] * x0.x + Ws[f0 + 1] * x0.y + Ws[f0 + 2] * x0.z + Ws[f0 + 3] * x0.w
             + Ws[16 + f0] * x1a + Ws[17 + f0] * x1b + Ws[18 + f0] * x1c + Ws[19 + f0] * x1d
             + Ws[32 + f0] * x2a + Ws[33 + f0] * x2b + Ws[34 + f0] * x2c + Ws[35 + f0] * x2d;
    float t1 = Ws[48 + f0] * x0.x + Ws[49 + f0] * x0.y + Ws[50 + f0] * x0.z + Ws[51 + f0] * x0.w
             + Ws[64 + f0] * x1a + Ws[65 + f0] * x1b + Ws[66 + f0] * x1c + Ws[67 + f0] * x1d
             + Ws[80 + f0] * x2a + Ws[81 + f0] * x2b + Ws[82 + f0] * x2c + Ws[83 + f0] * x2d;
    t0 += __shfl_xor(t0, 2, 4); t0 += __shfl_xor(t0, 1, 4);
    t1 += __shfl_xor(t1, 2, 4); t1 += __shfl_xor(t1, 1, 4);
    if (h == 0) {
        out[(size_t)n * 2 + 0] = fmaxf(t0, 0.f);
        out[(size_t)n * 2 + 1] = fmaxf(t1, 0.f);
    }
}

extern "C" void kernel_launch(void* const* d_in, const int* in_sizes, int n_in,
                              void* d_out, int out_size, void* d_ws, size_t ws_size,
                              hipStream_t stream) {
    const float* X0  = (const float*)d_in[0];
    const float* W   = (const float*)d_in[1];
    const int*   src = (const int*)d_in[2];
    const int*   dst = (const int*)d_in[3];
    const float* lm  = (const float*)d_in[4];
    float* out = (float*)d_out;

    // Workspace (~39 MB of 256MiB):
    // hxg[NBLK*HXW] | csort[NE] | es[NBUK*LCAP] | P[NN]
    // | Y0[(NN+1)*F bf16] | Y1[(NN+1)*F bf16]
    int*   hxg   = (int*)d_ws;
    int*   csort = hxg + (size_t)NBLK * HXW;
    int*   es    = csort + NE;
    unsigned int* P = (unsigned int*)(es + (size_t)NBUK * LCAP);
    unsigned short* Y0 = (unsigned short*)(P + NN);
    unsigned short* Y1 = Y0 + (size_t)(NN + 1) * F;

    const int gridP = (NN + 63) / 64;   // 1563

    k_lsort<<<NBLK, 512, 0, stream>>>(src, dst, hxg, csort);
    k_sort <<<NBUK, 512, 0, stream>>>(csort, hxg, X0, es, P, Y0, Y1);
    k_prop1<<<gridP, 256, 0, stream>>>(P, es, Y0, X0, lm, Y1);
    k_prop2<<<gridP, 256, 0, stream>>>(P, es, Y1, X0, lm, W, out);
}

// Round 18
// 160.401 us; speedup vs baseline: 1.0612x; 1.0612x over previous
//
#include <hip/hip_runtime.h>
#include <hip/hip_bf16.h>

// ChebConv K=3 GCN — Round 18: unbundle R17. Keep lsort register-stash +
// shfl-scan sort; REVERT props to R16's LDS-staged int4 indices.
// R17 post-mortem: +9us regression attributed to stage-free props — direct
// es reads put a ~200cy L2 index load in series with its gathers per batch,
// vs staged: one bulk coalesced 256-thread stage hides it block-wide.
// lsort stash (deletes 12.8MB re-read) and shfl scans (deletes 27 barriers)
// have no regression mechanism — kept.

#define NN   100000
#define NE   3200000
#define F    16
#define CB   128                  // dst nodes per bucket
#define NBUK 782                  // ceil(NN/CB)
#define ECHK 8192                 // edges per sort chunk
#define NBLK 391                  // ceil(NE/ECHK)
#define LCAP 5632                 // per-bucket es slot (padded mean ~4544, >12 sigma)
#define HXW  1025                 // hxg row width (1024 run starts + total)
#define PCAP 4608                 // staged padded edges per 64-node prop block

__device__ __forceinline__ float bflo(unsigned int u) {
    return __uint_as_float(u << 16);
}
__device__ __forceinline__ float bfhi(unsigned int u) {
    return __uint_as_float(u & 0xffff0000u);
}
__device__ __forceinline__ unsigned int f2bf(float f) {
    __hip_bfloat16 b = __float2bfloat16(f);
    return (unsigned int)*reinterpret_cast<unsigned short*>(&b);
}

// A1: per-chunk LDS counting sort by bucket -> chunk-major csort + run table hxg.
// (src,dst) int4 pairs stashed in registers between histogram and scatter.
__global__ __launch_bounds__(512) void k_lsort(const int* __restrict__ src,
        const int* __restrict__ dst, int* __restrict__ hxg, int* __restrict__ csort) {
    __shared__ __align__(16) int pk[ECHK];   // 32KB
    __shared__ int hx[HXW];
    __shared__ int cur[1024];
    __shared__ int csum[512];
    int t = threadIdx.x, blk = blockIdx.x;
    for (int j = t; j < 1024; j += 512) hx[j] = 0;
    __syncthreads();
    int s0 = blk * ECHK;
    int lim = min(s0 + ECHK, NE);
    int n4 = (lim - s0) >> 2;                // 2048 or 1280 (both /4)
    const int4* dst4 = (const int4*)(dst + s0);
    const int4* src4 = (const int4*)(src + s0);
    int4 dreg[4], sreg[4];
#pragma unroll
    for (int k = 0; k < 4; ++k) {
        int i = t + (k << 9);
        if (i < n4) {
            int4 d = dst4[i];
            int4 s = src4[i];
            dreg[k] = d; sreg[k] = s;
            atomicAdd(&hx[d.x >> 7], 1);
            atomicAdd(&hx[d.y >> 7], 1);
            atomicAdd(&hx[d.z >> 7], 1);
            atomicAdd(&hx[d.w >> 7], 1);
        }
    }
    __syncthreads();
    int b0 = t * 2;
    int c0 = hx[b0], c1 = hx[b0 + 1];
    csum[t] = c0 + c1;
    __syncthreads();
    for (int o = 1; o < 512; o <<= 1) {
        int add = (t >= o) ? csum[t - o] : 0;
        __syncthreads();
        csum[t] += add;
        __syncthreads();
    }
    int ce = csum[t] - (c0 + c1);
    hx[b0] = ce;  hx[b0 + 1] = ce + c0;
    cur[b0] = ce; cur[b0 + 1] = ce + c0;
    if (t == 511) hx[1024] = csum[511];
    __syncthreads();
    for (int j = t; j < HXW; j += 512)
        hxg[blk * HXW + j] = hx[j];
#pragma unroll
    for (int k = 0; k < 4; ++k) {
        int i = t + (k << 9);
        if (i < n4) {
            int4 d = dreg[k];
            int4 s = sreg[k];
            int pos;
            pos = atomicAdd(&cur[d.x >> 7], 1); pk[pos] = (s.x << 7) | (d.x & 127);
            pos = atomicAdd(&cur[d.y >> 7], 1); pk[pos] = (s.y << 7) | (d.y & 127);
            pos = atomicAdd(&cur[d.z >> 7], 1); pk[pos] = (s.z << 7) | (d.z & 127);
            pos = atomicAdd(&cur[d.w >> 7], 1); pk[pos] = (s.w << 7) | (d.w & 127);
        }
    }
    __syncthreads();
    int4* cs4 = (int4*)(csort + s0);
    const int4* pk4 = (const int4*)pk;
    for (int i = t; i < n4; i += 512)
        cs4[i] = pk4[i];
}

// A2: per-bucket exact dst sort. Cooperative 16-lane run gather into LDS,
// counting sort with 8-padded node lists (shfl scans), packed CSR, Y0, int4 es.
__global__ __launch_bounds__(512) void k_sort(const int* __restrict__ csort,
        const int* __restrict__ hxg, const float* __restrict__ X0,
        int* __restrict__ es, unsigned int* __restrict__ P,
        unsigned short* __restrict__ Y0, unsigned short* __restrict__ Y1) {
    __shared__ __align__(16) int pk[LCAP];    // 22KB: bucket-grouped (unsorted)
    __shared__ __align__(16) int pk2[LCAP];   // 22KB: dst-sorted, 8-padded
    __shared__ int dsc[512];        // inclusive scan of run lengths
    __shared__ int hS[NBLK];        // run start within chunk
    __shared__ short rls[NBLK];     // run length
    __shared__ int wsum[8];
    __shared__ int ws2[2];
    __shared__ int cnt[CB], loc[CB], cur[CB];
    __shared__ float nvs[CB];
    int b = blockIdx.x, t = threadIdx.x;
    int ln = t & 63, wv = t >> 6;
    int h0 = 0, rl = 0;
    if (t < NBLK) {
        h0 = hxg[t * HXW + b];      // adjacent pair
        rl = hxg[t * HXW + b + 1] - h0;
        hS[t] = h0;
        rls[t] = (short)(rl > 4096 ? 4096 : rl);
    }
    if (t < CB) cnt[t] = 0;
    if (b == 0 && t < 4) {          // zero sentinel rows
        ((uint2*)Y0)[(size_t)NN * 4 + t] = make_uint2(0u, 0u);
        ((uint2*)Y1)[(size_t)NN * 4 + t] = make_uint2(0u, 0u);
    }
    // wave shfl scan of run lengths (inclusive), cross-wave fixup
    int v = rl;
    for (int o = 1; o < 64; o <<= 1) {
        int up = __shfl_up(v, o, 64);
        if (ln >= o) v += up;
    }
    if (ln == 63) wsum[wv] = v;
    __syncthreads();
    if (t == 0) {
        int acc = 0;
        for (int i = 0; i < 8; ++i) { int x = wsum[i]; wsum[i] = acc; acc += x; }
    }
    __syncthreads();
    v += wsum[wv];
    dsc[t] = v;
    __syncthreads();
    int len = dsc[511];
    if (len > LCAP) len = LCAP;
    // cooperative run gather: 32 groups x 16 lanes, coalesced per run
    int g = t >> 4, lane = t & 15;
    for (int c = g; c < NBLK; c += 32) {
        int rlc = rls[c];
        if (rlc == 0) continue;
        int dpos = dsc[c] - rlc;
        if (dpos >= LCAP) continue;
        if (dpos + rlc > LCAP) rlc = LCAP - dpos;
        int sb = c * ECHK + hS[c];
        for (int l = lane; l < rlc; l += 16)
            pk[dpos + l] = csort[sb + l];
    }
    __syncthreads();
    // count dst occupancy
    for (int i = t; i < len; i += 512)
        atomicAdd(&cnt[pk[i] & 127], 1);
    __syncthreads();
    // shfl scan of 8-padded counts -> exclusive offsets (multiples of 8)
    int pc = 0, vv = 0;
    if (t < CB) { pc = (cnt[t] + 7) & ~7; vv = pc; }
    for (int o = 1; o < 64; o <<= 1) {
        int up = __shfl_up(vv, o, 64);
        if (ln >= o) vv += up;
    }
    if (t < CB && ln == 63) ws2[wv] = vv;
    __syncthreads();
    if (t < CB) {
        if (wv == 1) vv += ws2[0];
        int excl = vv - pc;
        loc[t] = excl;
        cur[t] = excl;
        int n = b * CB + t;
        if (n < NN) {
            unsigned dgc = cnt[t] > 1023 ? 1023u : (unsigned)cnt[t];
            P[n] = ((unsigned)((b * LCAP + excl) >> 3) << 10) | dgc;  // off/8 | deg
            nvs[t] = rsqrtf((float)(cnt[t] < 1 ? 1 : cnt[t]));
        }
    }
    __syncthreads();
    int plen = loc[CB - 1] + ((cnt[CB - 1] + 7) & ~7);
    if (plen > LCAP) plen = LCAP;
    // pad fill (disjoint from scatter region)
    if (t < CB) {
        int e0 = loc[t] + cnt[t];
        int e1 = loc[t] + ((cnt[t] + 7) & ~7);
        for (int i = e0; i < e1 && i < LCAP; ++i) pk2[i] = NN;
    }
    // dst-sort scatter from LDS pk
    for (int i = t; i < len; i += 512) {
        int p = pk[i];
        int pos = atomicAdd(&cur[p & 127], 1);
        if (pos < LCAP) pk2[pos] = p >> 7;
    }
    // Y0 for this bucket's nodes (coalesced)
    for (int j = t; j < CB * 4; j += 512) {
        int dl = j >> 2;
        int n = b * CB + dl;
        if (n < NN) {
            float nv = nvs[dl];
            size_t g4 = (size_t)n * 4 + (j & 3);
            float4 x0 = ((const float4*)X0)[g4];
            uint2 o;
            o.x = f2bf(x0.x * nv) | (f2bf(x0.y * nv) << 16);
            o.y = f2bf(x0.z * nv) | (f2bf(x0.w * nv) << 16);
            ((uint2*)Y0)[g4] = o;
        }
    }
    __syncthreads();
    // int4 es writeout (fixed per-bucket slot; base 16B-aligned, plen % 8 == 0)
    int4* es4 = (int4*)(es + b * LCAP);
    const int4* p24 = (const int4*)pk2;
    int p4 = plen >> 2;
    for (int i = t; i < p4; i += 512)
        es4[i] = p24[i];
}

// A3: prop1 (R16 form). Padded es slice staged in LDS via int4; indices read
// as aligned int4 pairs; full 8-edge batches (sentinel -> zero row).
__global__ __launch_bounds__(256) void k_prop1(const unsigned int* __restrict__ P,
        const int* __restrict__ es, const unsigned short* __restrict__ Y0,
        const float* __restrict__ X0, const float* __restrict__ lm,
        unsigned short* __restrict__ Y1) {
    __shared__ __align__(16) int sidx[PCAP];   // 18KB
    int blk = blockIdx.x, t = threadIdx.x;
    int b = blk >> 1, half = blk & 1;
    int n0 = b * CB + half * 64;
    if (n0 >= NN) return;           // uniform per block
    unsigned pk0 = P[n0];
    int nL = min(n0 + 63, NN - 1);
    unsigned pkL = P[nL];
    int st = (int)(pk0 >> 10) << 3;
    int en = ((int)(pkL >> 10) << 3) + (int)(((pkL & 1023u) + 7u) & ~7u);
    int slen = en - st;
    if (slen > PCAP) slen = PCAP;
    const int4* esg = (const int4*)(es + st);
    int4* sid4 = (int4*)sidx;
    int s4 = slen >> 2;
    for (int i = t; i < s4; i += 256)
        sid4[i] = esg[i];
    __syncthreads();
    int n = n0 + (t >> 2), h = t & 3;
    if (n >= NN) return;
    unsigned pkn = P[n];
    int beg = ((int)(pkn >> 10) << 3) - st;    // multiple of 8
    int dg = (int)(pkn & 1023u);
    int nb = (dg + 7) >> 3;
    const uint2* Yv = (const uint2*)Y0;
    float a0 = 0.f, a1 = 0.f, a2 = 0.f, a3 = 0.f;
    for (int bb = 0; bb < nb; ++bb) {
        int e0 = beg + bb * 8;
        int4 ia = *(const int4*)&sidx[e0];
        int4 ib = *(const int4*)&sidx[e0 + 4];
#define ACC(S) { uint2 u = Yv[(size_t)(S) * 4 + h]; \
                 a0 += bflo(u.x); a1 += bfhi(u.x); \
                 a2 += bflo(u.y); a3 += bfhi(u.y); }
        ACC(ia.x) ACC(ia.y) ACC(ia.z) ACC(ia.w)
        ACC(ib.x) ACC(ib.y) ACC(ib.z) ACC(ib.w)
    }
    float nv = rsqrtf((float)(dg < 1 ? 1 : dg));
    float r  = 2.0f / lm[0];
    float k1 = -r * nv, k2 = r - 1.0f;
    int tid4 = n * 4 + h;
    float4 x0 = ((const float4*)X0)[tid4];
    float x1a = k1 * a0 + k2 * x0.x;
    float x1b = k1 * a1 + k2 * x0.y;
    float x1c = k1 * a2 + k2 * x0.z;
    float x1d = k1 * a3 + k2 * x0.w;
    uint2 o;
    o.x = f2bf(nv * x1a) | (f2bf(nv * x1b) << 16);
    o.y = f2bf(nv * x1c) | (f2bf(nv * x1d) << 16);
    ((uint2*)Y1)[tid4] = o;
}

// A4: prop2 + epilogue (R16 form): x2 + [x0|x1|x2]@W^T + relu.
__global__ __launch_bounds__(256) void k_prop2(const unsigned int* __restrict__ P,
        const int* __restrict__ es, const unsigned short* __restrict__ Y1,
        const float* __restrict__ X0, const float* __restrict__ lm,
        const float* __restrict__ W, float* __restrict__ out) {
    __shared__ __align__(16) int sidx[PCAP];   // 18KB
    __shared__ float Ws[96];
    int blk = blockIdx.x, t = threadIdx.x;
    int b = blk >> 1, half = blk & 1;
    int n0 = b * CB + half * 64;
    if (n0 >= NN) return;           // uniform per block
    if (t < 96) Ws[t] = W[t];
    unsigned pk0 = P[n0];
    int nL = min(n0 + 63, NN - 1);
    unsigned pkL = P[nL];
    int st = (int)(pk0 >> 10) << 3;
    int en = ((int)(pkL >> 10) << 3) + (int)(((pkL & 1023u) + 7u) & ~7u);
    int slen = en - st;
    if (slen > PCAP) slen = PCAP;
    const int4* esg = (const int4*)(es + st);
    int4* sid4 = (int4*)sidx;
    int s4 = slen >> 2;
    for (int i = t; i < s4; i += 256)
        sid4[i] = esg[i];
    __syncthreads();
    int n = n0 + (t >> 2), h = t & 3;
    if (n >= NN) return;
    unsigned pkn = P[n];
    int beg = ((int)(pkn >> 10) << 3) - st;
    int dg = (int)(pkn & 1023u);
    int nb = (dg + 7) >> 3;
    const uint2* Yv = (const uint2*)Y1;
    float a0 = 0.f, a1 = 0.f, a2 = 0.f, a3 = 0.f;
    for (int bb = 0; bb < nb; ++bb) {
        int e0 = beg + bb * 8;
        int4 ia = *(const int4*)&sidx[e0];
        int4 ib = *(const int4*)&sidx[e0 + 4];
        ACC(ia.x) ACC(ia.y) ACC(ia.z) ACC(ia.w)
        ACC(ib.x) ACC(ib.y) ACC(ib.z) ACC(ib.w)
    }
    int dc = dg < 1 ? 1 : dg;
    float nv = rsqrtf((float)dc);
    float rn = sqrtf((float)dc);    // 1/nv without rcp
    float r  = 2.0f / lm[0];
    int tid4 = n * 4 + h;
    float4 x0 = ((const float4*)X0)[tid4];
    uint2 uy = ((const uint2*)Y1)[tid4];
    float x1a = bflo(uy.x) * rn, x1b = bfhi(uy.x) * rn;
    float x1c = bflo(uy.y) * rn, x1d = bfhi(uy.y) * rn;
    float c1 = -2.0f * r * nv, c2 = 2.0f * (r - 1.0f);
    float x2a = c1 * a0 + c2 * x1a - x0.x;
    float x2b = c1 * a1 + c2 * x1b - x0.y;
    float x2c = c1 * a2 + c2 * x1c - x0.z;
    float x2d = c1 * a3 + c2 * x1d - x0.w;
    int f0 = 4 * h;
    float t0 = Ws[f0] * x0.x + Ws[f0 + 1] * x0.y + Ws[f0 + 2] * x0.z + Ws[f0 + 3] * x0.w
             + Ws[16 + f0] * x1a + Ws[17 + f0] * x1b + Ws[18 + f0] * x1c + Ws[19 + f0] * x1d
             + Ws[32 + f0] * x2a + Ws[33 + f0] * x2b + Ws[34 + f0] * x2c + Ws[35 + f0] * x2d;
    float t1 = Ws[48 + f0] * x0.x + Ws[49 + f0] * x0.y + Ws[50 + f0] * x0.z + Ws[51 + f0] * x0.w
             + Ws[64 + f0] * x1a + Ws[65 + f0] * x1b + Ws[66 + f0] * x1c + Ws[67 + f0] * x1d
             + Ws[80 + f0] * x2a + Ws[81 + f0] * x2b + Ws[82 + f0] * x2c + Ws[83 + f0] * x2d;
    t0 += __shfl_xor(t0, 2, 4); t0 += __shfl_xor(t0, 1, 4);
    t1 += __shfl_xor(t1, 2, 4); t1 += __shfl_xor(t1, 1, 4);
    if (h == 0) {
        out[(size_t)n * 2 + 0] = fmaxf(t0, 0.f);
        out[(size_t)n * 2 + 1] = fmaxf(t1, 0.f);
    }
}

extern "C" void kernel_launch(void* const* d_in, const int* in_sizes, int n_in,
                              void* d_out, int out_size, void* d_ws, size_t ws_size,
                              hipStream_t stream) {
    const float* X0  = (const float*)d_in[0];
    const float* W   = (const float*)d_in[1];
    const int*   src = (const int*)d_in[2];
    const int*   dst = (const int*)d_in[3];
    const float* lm  = (const float*)d_in[4];
    float* out = (float*)d_out;

    // Workspace (~39 MB of 256MiB):
    // hxg[NBLK*HXW] | csort[NE] | es[NBUK*LCAP] | P[NN]
    // | Y0[(NN+1)*F bf16] | Y1[(NN+1)*F bf16]
    int*   hxg   = (int*)d_ws;
    int*   csort = hxg + (size_t)NBLK * HXW;
    int*   es    = csort + NE;
    unsigned int* P = (unsigned int*)(es + (size_t)NBUK * LCAP);
    unsigned short* Y0 = (unsigned short*)(P + NN);
    unsigned short* Y1 = Y0 + (size_t)(NN + 1) * F;

    k_lsort<<<NBLK, 512, 0, stream>>>(src, dst, hxg, csort);
    k_sort <<<NBUK, 512, 0, stream>>>(csort, hxg, X0, es, P, Y0, Y1);
    k_prop1<<<NBUK * 2, 256, 0, stream>>>(P, es, Y0, X0, lm, Y1);
    k_prop2<<<NBUK * 2, 256, 0, stream>>>(P, es, Y1, X0, lm, W, out);
}

// Round 19
// 158.955 us; speedup vs baseline: 1.0709x; 1.0091x over previous
//
#include <hip/hip_runtime.h>
#include <hip/hip_bf16.h>

// ChebConv K=3 GCN — Round 19: paired-edge uint4 gathers in props + shfl-scan lsort.
// R18 post-mortem: 160.4us best; props ~60-70us of total. This round halves
// prop gather-load count at constant wave count: lane h>>1 takes even/odd
// edges, lane h&1 takes the 16B half-row -> 4 uint4 gathers per 8-edge batch
// per lane (was 8 uint2). Epilogue fixup: shfl_xor(2) pair-sum + width-4
// shfl redistribution back to 4-feats-per-lane, then the proven epilogue.
// lsort's 512-wide H-S scan (18 barriers) replaced by the k_sort-proven
// wave shfl scan (3 barriers).

#define NN   100000
#define NE   3200000
#define F    16
#define CB   128                  // dst nodes per bucket
#define NBUK 782                  // ceil(NN/CB)
#define ECHK 8192                 // edges per sort chunk
#define NBLK 391                  // ceil(NE/ECHK)
#define LCAP 5632                 // per-bucket es slot (padded mean ~4544, >12 sigma)
#define HXW  1025                 // hxg row width (1024 run starts + total)
#define PCAP 4608                 // staged padded edges per 64-node prop block

__device__ __forceinline__ float bflo(unsigned int u) {
    return __uint_as_float(u << 16);
}
__device__ __forceinline__ float bfhi(unsigned int u) {
    return __uint_as_float(u & 0xffff0000u);
}
__device__ __forceinline__ unsigned int f2bf(float f) {
    __hip_bfloat16 b = __float2bfloat16(f);
    return (unsigned int)*reinterpret_cast<unsigned short*>(&b);
}

// A1: per-chunk LDS counting sort by bucket -> chunk-major csort + run table hxg.
// Register-stashed (src,dst); wave shfl scan (3 barriers).
__global__ __launch_bounds__(512) void k_lsort(const int* __restrict__ src,
        const int* __restrict__ dst, int* __restrict__ hxg, int* __restrict__ csort) {
    __shared__ __align__(16) int pk[ECHK];   // 32KB
    __shared__ int hx[HXW];
    __shared__ int cur[1024];
    __shared__ int wsum[8];
    int t = threadIdx.x, blk = blockIdx.x;
    int ln = t & 63, wv = t >> 6;
    for (int j = t; j < 1024; j += 512) hx[j] = 0;
    __syncthreads();
    int s0 = blk * ECHK;
    int lim = min(s0 + ECHK, NE);
    int n4 = (lim - s0) >> 2;                // 2048 or 1280 (both /4)
    const int4* dst4 = (const int4*)(dst + s0);
    const int4* src4 = (const int4*)(src + s0);
    int4 dreg[4], sreg[4];
#pragma unroll
    for (int k = 0; k < 4; ++k) {
        int i = t + (k << 9);
        if (i < n4) {
            int4 d = dst4[i];
            int4 s = src4[i];
            dreg[k] = d; sreg[k] = s;
            atomicAdd(&hx[d.x >> 7], 1);
            atomicAdd(&hx[d.y >> 7], 1);
            atomicAdd(&hx[d.z >> 7], 1);
            atomicAdd(&hx[d.w >> 7], 1);
        }
    }
    __syncthreads();
    int b0 = t * 2;
    int c0 = hx[b0], c1 = hx[b0 + 1];
    // wave shfl scan of per-thread bucket-pair sums, cross-wave fixup
    int v = c0 + c1;
    for (int o = 1; o < 64; o <<= 1) {
        int up = __shfl_up(v, o, 64);
        if (ln >= o) v += up;
    }
    if (ln == 63) wsum[wv] = v;
    __syncthreads();
    if (t == 0) {
        int acc = 0;
        for (int i = 0; i < 8; ++i) { int x = wsum[i]; wsum[i] = acc; acc += x; }
    }
    __syncthreads();
    v += wsum[wv];                  // inclusive over block
    int ce = v - (c0 + c1);         // exclusive
    hx[b0] = ce;  hx[b0 + 1] = ce + c0;
    cur[b0] = ce; cur[b0 + 1] = ce + c0;
    if (t == 511) hx[1024] = v;     // chunk total
    __syncthreads();
    for (int j = t; j < HXW; j += 512)
        hxg[blk * HXW + j] = hx[j];
#pragma unroll
    for (int k = 0; k < 4; ++k) {
        int i = t + (k << 9);
        if (i < n4) {
            int4 d = dreg[k];
            int4 s = sreg[k];
            int pos;
            pos = atomicAdd(&cur[d.x >> 7], 1); pk[pos] = (s.x << 7) | (d.x & 127);
            pos = atomicAdd(&cur[d.y >> 7], 1); pk[pos] = (s.y << 7) | (d.y & 127);
            pos = atomicAdd(&cur[d.z >> 7], 1); pk[pos] = (s.z << 7) | (d.z & 127);
            pos = atomicAdd(&cur[d.w >> 7], 1); pk[pos] = (s.w << 7) | (d.w & 127);
        }
    }
    __syncthreads();
    int4* cs4 = (int4*)(csort + s0);
    const int4* pk4 = (const int4*)pk;
    for (int i = t; i < n4; i += 512)
        cs4[i] = pk4[i];
}

// A2: per-bucket exact dst sort (unchanged from R18).
__global__ __launch_bounds__(512) void k_sort(const int* __restrict__ csort,
        const int* __restrict__ hxg, const float* __restrict__ X0,
        int* __restrict__ es, unsigned int* __restrict__ P,
        unsigned short* __restrict__ Y0, unsigned short* __restrict__ Y1) {
    __shared__ __align__(16) int pk[LCAP];    // 22KB: bucket-grouped (unsorted)
    __shared__ __align__(16) int pk2[LCAP];   // 22KB: dst-sorted, 8-padded
    __shared__ int dsc[512];
    __shared__ int hS[NBLK];
    __shared__ short rls[NBLK];
    __shared__ int wsum[8];
    __shared__ int ws2[2];
    __shared__ int cnt[CB], loc[CB], cur[CB];
    __shared__ float nvs[CB];
    int b = blockIdx.x, t = threadIdx.x;
    int ln = t & 63, wv = t >> 6;
    int h0 = 0, rl = 0;
    if (t < NBLK) {
        h0 = hxg[t * HXW + b];
        rl = hxg[t * HXW + b + 1] - h0;
        hS[t] = h0;
        rls[t] = (short)(rl > 4096 ? 4096 : rl);
    }
    if (t < CB) cnt[t] = 0;
    if (b == 0 && t < 4) {          // zero sentinel rows
        ((uint2*)Y0)[(size_t)NN * 4 + t] = make_uint2(0u, 0u);
        ((uint2*)Y1)[(size_t)NN * 4 + t] = make_uint2(0u, 0u);
    }
    int v = rl;
    for (int o = 1; o < 64; o <<= 1) {
        int up = __shfl_up(v, o, 64);
        if (ln >= o) v += up;
    }
    if (ln == 63) wsum[wv] = v;
    __syncthreads();
    if (t == 0) {
        int acc = 0;
        for (int i = 0; i < 8; ++i) { int x = wsum[i]; wsum[i] = acc; acc += x; }
    }
    __syncthreads();
    v += wsum[wv];
    dsc[t] = v;
    __syncthreads();
    int len = dsc[511];
    if (len > LCAP) len = LCAP;
    int g = t >> 4, lane = t & 15;
    for (int c = g; c < NBLK; c += 32) {
        int rlc = rls[c];
        if (rlc == 0) continue;
        int dpos = dsc[c] - rlc;
        if (dpos >= LCAP) continue;
        if (dpos + rlc > LCAP) rlc = LCAP - dpos;
        int sb = c * ECHK + hS[c];
        for (int l = lane; l < rlc; l += 16)
            pk[dpos + l] = csort[sb + l];
    }
    __syncthreads();
    for (int i = t; i < len; i += 512)
        atomicAdd(&cnt[pk[i] & 127], 1);
    __syncthreads();
    int pc = 0, vv = 0;
    if (t < CB) { pc = (cnt[t] + 7) & ~7; vv = pc; }
    for (int o = 1; o < 64; o <<= 1) {
        int up = __shfl_up(vv, o, 64);
        if (ln >= o) vv += up;
    }
    if (t < CB && ln == 63) ws2[wv] = vv;
    __syncthreads();
    if (t < CB) {
        if (wv == 1) vv += ws2[0];
        int excl = vv - pc;
        loc[t] = excl;
        cur[t] = excl;
        int n = b * CB + t;
        if (n < NN) {
            unsigned dgc = cnt[t] > 1023 ? 1023u : (unsigned)cnt[t];
            P[n] = ((unsigned)((b * LCAP + excl) >> 3) << 10) | dgc;  // off/8 | deg
            nvs[t] = rsqrtf((float)(cnt[t] < 1 ? 1 : cnt[t]));
        }
    }
    __syncthreads();
    int plen = loc[CB - 1] + ((cnt[CB - 1] + 7) & ~7);
    if (plen > LCAP) plen = LCAP;
    if (t < CB) {
        int e0 = loc[t] + cnt[t];
        int e1 = loc[t] + ((cnt[t] + 7) & ~7);
        for (int i = e0; i < e1 && i < LCAP; ++i) pk2[i] = NN;
    }
    for (int i = t; i < len; i += 512) {
        int p = pk[i];
        int pos = atomicAdd(&cur[p & 127], 1);
        if (pos < LCAP) pk2[pos] = p >> 7;
    }
    for (int j = t; j < CB * 4; j += 512) {
        int dl = j >> 2;
        int n = b * CB + dl;
        if (n < NN) {
            float nv = nvs[dl];
            size_t g4 = (size_t)n * 4 + (j & 3);
            float4 x0 = ((const float4*)X0)[g4];
            uint2 o;
            o.x = f2bf(x0.x * nv) | (f2bf(x0.y * nv) << 16);
            o.y = f2bf(x0.z * nv) | (f2bf(x0.w * nv) << 16);
            ((uint2*)Y0)[g4] = o;
        }
    }
    __syncthreads();
    int4* es4 = (int4*)(es + b * LCAP);
    const int4* p24 = (const int4*)pk2;
    int p4 = plen >> 2;
    for (int i = t; i < p4; i += 512)
        es4[i] = p24[i];
}

// Paired-edge uint4 gather: lane (h>>1) = edge parity, (h&1) = half-row.
// 4 uint4 gathers per 8-edge batch per lane. Returns 8 accumulators.
#define GATHER8(Yv4, half, par, sidx, beg, nb, A)                          \
    for (int bb = 0; bb < nb; ++bb) {                                      \
        int e0 = beg + bb * 8;                                             \
        int4 ia = *(const int4*)&sidx[e0];                                 \
        int4 ib = *(const int4*)&sidx[e0 + 4];                             \
        int i0 = par ? ia.y : ia.x;                                        \
        int i1 = par ? ia.w : ia.z;                                        \
        int i2 = par ? ib.y : ib.x;                                        \
        int i3 = par ? ib.w : ib.z;                                        \
        uint4 u;                                                           \
        u = Yv4[(size_t)i0 * 2 + half];                                    \
        A##0 += bflo(u.x); A##1 += bfhi(u.x); A##2 += bflo(u.y); A##3 += bfhi(u.y); \
        A##4 += bflo(u.z); A##5 += bfhi(u.z); A##6 += bflo(u.w); A##7 += bfhi(u.w); \
        u = Yv4[(size_t)i1 * 2 + half];                                    \
        A##0 += bflo(u.x); A##1 += bfhi(u.x); A##2 += bflo(u.y); A##3 += bfhi(u.y); \
        A##4 += bflo(u.z); A##5 += bfhi(u.z); A##6 += bflo(u.w); A##7 += bfhi(u.w); \
        u = Yv4[(size_t)i2 * 2 + half];                                    \
        A##0 += bflo(u.x); A##1 += bfhi(u.x); A##2 += bflo(u.y); A##3 += bfhi(u.y); \
        A##4 += bflo(u.z); A##5 += bfhi(u.z); A##6 += bflo(u.w); A##7 += bfhi(u.w); \
        u = Yv4[(size_t)i3 * 2 + half];                                    \
        A##0 += bflo(u.x); A##1 += bfhi(u.x); A##2 += bflo(u.y); A##3 += bfhi(u.y); \
        A##4 += bflo(u.z); A##5 += bfhi(u.z); A##6 += bflo(u.w); A##7 += bfhi(u.w); \
    }

// Pair-sum (even+odd edge lanes) then redistribute to 4-feats-per-lane.
#define REDUCE_REDIST(A, h, r0, r1, r2, r3)                                \
    A##0 += __shfl_xor(A##0, 2, 4); A##1 += __shfl_xor(A##1, 2, 4);        \
    A##2 += __shfl_xor(A##2, 2, 4); A##3 += __shfl_xor(A##3, 2, 4);        \
    A##4 += __shfl_xor(A##4, 2, 4); A##5 += __shfl_xor(A##5, 2, 4);        \
    A##6 += __shfl_xor(A##6, 2, 4); A##7 += __shfl_xor(A##7, 2, 4);        \
    {                                                                      \
        int sl = h >> 1;                                                   \
        float lo, hi;                                                      \
        lo = __shfl(A##0, sl, 4); hi = __shfl(A##4, sl, 4); r0 = (h & 1) ? hi : lo; \
        lo = __shfl(A##1, sl, 4); hi = __shfl(A##5, sl, 4); r1 = (h & 1) ? hi : lo; \
        lo = __shfl(A##2, sl, 4); hi = __shfl(A##6, sl, 4); r2 = (h & 1) ? hi : lo; \
        lo = __shfl(A##3, sl, 4); hi = __shfl(A##7, sl, 4); r3 = (h & 1) ? hi : lo; \
    }

// A3: prop1. LDS-staged int4 indices (R16/R18-proven), paired-edge uint4 gathers.
__global__ __launch_bounds__(256) void k_prop1(const unsigned int* __restrict__ P,
        const int* __restrict__ es, const unsigned short* __restrict__ Y0,
        const float* __restrict__ X0, const float* __restrict__ lm,
        unsigned short* __restrict__ Y1) {
    __shared__ __align__(16) int sidx[PCAP];   // 18KB
    int blk = blockIdx.x, t = threadIdx.x;
    int b = blk >> 1, half_b = blk & 1;
    int n0 = b * CB + half_b * 64;
    if (n0 >= NN) return;           // uniform per block
    unsigned pk0 = P[n0];
    int nL = min(n0 + 63, NN - 1);
    unsigned pkL = P[nL];
    int st = (int)(pk0 >> 10) << 3;
    int en = ((int)(pkL >> 10) << 3) + (int)(((pkL & 1023u) + 7u) & ~7u);
    int slen = en - st;
    if (slen > PCAP) slen = PCAP;
    const int4* esg = (const int4*)(es + st);
    int4* sid4 = (int4*)sidx;
    int s4 = slen >> 2;
    for (int i = t; i < s4; i += 256)
        sid4[i] = esg[i];
    __syncthreads();
    int n = n0 + (t >> 2), h = t & 3;
    if (n >= NN) return;
    unsigned pkn = P[n];
    int beg = ((int)(pkn >> 10) << 3) - st;    // multiple of 8
    int dg = (int)(pkn & 1023u);
    int nb = (dg + 7) >> 3;
    const uint4* Yv4 = (const uint4*)Y0;
    int half = h & 1, par = (h >> 1) & 1;
    float a0 = 0.f, a1 = 0.f, a2 = 0.f, a3 = 0.f,
          a4 = 0.f, a5 = 0.f, a6 = 0.f, a7 = 0.f;
    GATHER8(Yv4, half, par, sidx, beg, nb, a)
    float r0, r1, r2, r3;
    REDUCE_REDIST(a, h, r0, r1, r2, r3)
    float nv = rsqrtf((float)(dg < 1 ? 1 : dg));
    float r  = 2.0f / lm[0];
    float k1 = -r * nv, k2 = r - 1.0f;
    int tid4 = n * 4 + h;
    float4 x0 = ((const float4*)X0)[tid4];
    float x1a = k1 * r0 + k2 * x0.x;
    float x1b = k1 * r1 + k2 * x0.y;
    float x1c = k1 * r2 + k2 * x0.z;
    float x1d = k1 * r3 + k2 * x0.w;
    uint2 o;
    o.x = f2bf(nv * x1a) | (f2bf(nv * x1b) << 16);
    o.y = f2bf(nv * x1c) | (f2bf(nv * x1d) << 16);
    ((uint2*)Y1)[tid4] = o;
}

// A4: prop2 + epilogue: x2 + [x0|x1|x2]@W^T + relu. Same gather scheme.
__global__ __launch_bounds__(256) void k_prop2(const unsigned int* __restrict__ P,
        const int* __restrict__ es, const unsigned short* __restrict__ Y1,
        const float* __restrict__ X0, const float* __restrict__ lm,
        const float* __restrict__ W, float* __restrict__ out) {
    __shared__ __align__(16) int sidx[PCAP];   // 18KB
    __shared__ float Ws[96];
    int blk = blockIdx.x, t = threadIdx.x;
    int b = blk >> 1, half_b = blk & 1;
    int n0 = b * CB + half_b * 64;
    if (n0 >= NN) return;           // uniform per block
    if (t < 96) Ws[t] = W[t];
    unsigned pk0 = P[n0];
    int nL = min(n0 + 63, NN - 1);
    unsigned pkL = P[nL];
    int st = (int)(pk0 >> 10) << 3;
    int en = ((int)(pkL >> 10) << 3) + (int)(((pkL & 1023u) + 7u) & ~7u);
    int slen = en - st;
    if (slen > PCAP) slen = PCAP;
    const int4* esg = (const int4*)(es + st);
    int4* sid4 = (int4*)sidx;
    int s4 = slen >> 2;
    for (int i = t; i < s4; i += 256)
        sid4[i] = esg[i];
    __syncthreads();
    int n = n0 + (t >> 2), h = t & 3;
    if (n >= NN) return;
    unsigned pkn = P[n];
    int beg = ((int)(pkn >> 10) << 3) - st;
    int dg = (int)(pkn & 1023u);
    int nb = (dg + 7) >> 3;
    const uint4* Yv4 = (const uint4*)Y1;
    int half = h & 1, par = (h >> 1) & 1;
    float a0 = 0.f, a1 = 0.f, a2 = 0.f, a3 = 0.f,
          a4 = 0.f, a5 = 0.f, a6 = 0.f, a7 = 0.f;
    GATHER8(Yv4, half, par, sidx, beg, nb, a)
    float r0, r1, r2, r3;
    REDUCE_REDIST(a, h, r0, r1, r2, r3)
    int dc = dg < 1 ? 1 : dg;
    float nv = rsqrtf((float)dc);
    float rn = sqrtf((float)dc);    // 1/nv without rcp
    float r  = 2.0f / lm[0];
    int tid4 = n * 4 + h;
    float4 x0 = ((const float4*)X0)[tid4];
    uint2 uy = ((const uint2*)Y1)[tid4];
    float x1a = bflo(uy.x) * rn, x1b = bfhi(uy.x) * rn;
    float x1c = bflo(uy.y) * rn, x1d = bfhi(uy.y) * rn;
    float c1 = -2.0f * r * nv, c2 = 2.0f * (r - 1.0f);
    float x2a = c1 * r0 + c2 * x1a - x0.x;
    float x2b = c1 * r1 + c2 * x1b - x0.y;
    float x2c = c1 * r2 + c2 * x1c - x0.z;
    float x2d = c1 * r3 + c2 * x1d - x0.w;
    int f0 = 4 * h;
    float t0 = Ws[f0] * x0.x + Ws[f0 + 1] * x0.y + Ws[f0 + 2] * x0.z + Ws[f0 + 3] * x0.w
             + Ws[16 + f0] * x1a + Ws[17 + f0] * x1b + Ws[18 + f0] * x1c + Ws[19 + f0] * x1d
             + Ws[32 + f0] * x2a + Ws[33 + f0] * x2b + Ws[34 + f0] * x2c + Ws[35 + f0] * x2d;
    float t1 = Ws[48 + f0] * x0.x + Ws[49 + f0] * x0.y + Ws[50 + f0] * x0.z + Ws[51 + f0] * x0.w
             + Ws[64 + f0] * x1a + Ws[65 + f0] * x1b + Ws[66 + f0] * x1c + Ws[67 + f0] * x1d
             + Ws[80 + f0] * x2a + Ws[81 + f0] * x2b + Ws[82 + f0] * x2c + Ws[83 + f0] * x2d;
    t0 += __shfl_xor(t0, 2, 4); t0 += __shfl_xor(t0, 1, 4);
    t1 += __shfl_xor(t1, 2, 4); t1 += __shfl_xor(t1, 1, 4);
    if (h == 0) {
        out[(size_t)n * 2 + 0] = fmaxf(t0, 0.f);
        out[(size_t)n * 2 + 1] = fmaxf(t1, 0.f);
    }
}

extern "C" void kernel_launch(void* const* d_in, const int* in_sizes, int n_in,
                              void* d_out, int out_size, void* d_ws, size_t ws_size,
                              hipStream_t stream) {
    const float* X0  = (const float*)d_in[0];
    const float* W   = (const float*)d_in[1];
    const int*   src = (const int*)d_in[2];
    const int*   dst = (const int*)d_in[3];
    const float* lm  = (const float*)d_in[4];
    float* out = (float*)d_out;

    // Workspace (~39 MB of 256MiB):
    // hxg[NBLK*HXW] | csort[NE] | es[NBUK*LCAP] | P[NN]
    // | Y0[(NN+1)*F bf16] | Y1[(NN+1)*F bf16]
    int*   hxg   = (int*)d_ws;
    int*   csort = hxg + (size_t)NBLK * HXW;
    int*   es    = csort + NE;
    unsigned int* P = (unsigned int*)(es + (size_t)NBUK * LCAP);
    unsigned short* Y0 = (unsigned short*)(P + NN);
    unsigned short* Y1 = Y0 + (size_t)(NN + 1) * F;

    k_lsort<<<NBLK, 512, 0, stream>>>(src, dst, hxg, csort);
    k_sort <<<NBUK, 512, 0, stream>>>(csort, hxg, X0, es, P, Y0, Y1);
    k_prop1<<<NBUK * 2, 256, 0, stream>>>(P, es, Y0, X0, lm, Y1);
    k_prop2<<<NBUK * 2, 256, 0, stream>>>(P, es, Y1, X0, lm, W, out);
}